// Round 7
// baseline (155.670 us; speedup 1.0000x reference)
//
#include <hip/hip_runtime.h>

// Problem constants (fixed by reference setup_inputs)
#define N_PRE 8192
#define N_CUR 16384
#define KNN   8

// Workspace layout (bytes):
//   [0,    64K) : c2p  u32[N_CUR]     nearest-pre index per cur point
//   [64K, 192K) : pre4 float4[N_PRE]  (-2px, -2py, -2pz, |p|^2)
//   [192K,448K) : cur4 float4[N_CUR]  ( cx,   cy,   cz,  |c|^2)
//
// Comparator trick: for a fixed query q, ordering by true sqdist equals
// ordering by (|cand|^2 - 2 cand.q)  -> 3 FMA per candidate.
// d can be NEGATIVE -> monotone float->u32 key map for all key compares.
//
// R7 (work ledger from R4/R6: fast path ~7us, events ~8us unsplit,
// ds_read_b128 service 20.5us/CU at P=2 -> LDS pipe is the floor):
//  B: UNSPLIT (R6's cur-split doubled event work: 44.5us VALU-cycles vs
//     R4's 27), P=4 pres/wave halves ds_read service to ~10us.
//     256-thread blocks -> 2 independent blocks/CU (decoupled barriers);
//     depth-1 register prefetch of the next candidate chunk issued BEFORE
//     the pop calls (the ballot while-loop blocks compiler hoisting).
//     DPP row-replication => finalize all 4 lists in parallel (row r
//     handles list r).
//  A: R6 verbatim (~10us measured; never in top-5).

#define MAPPED_INF 0xFF800000u  // monotone key of +inf (empty-slot sentinel)

__device__ __forceinline__ unsigned key_of_bits(unsigned b) {
    return b ^ (0x80000000u | (unsigned)((int)b >> 31));
}
__device__ __forceinline__ float float_of_key(unsigned k) {
    unsigned b = k ^ (0x80000000u | ~(unsigned)((int)k >> 31));
    return __uint_as_float(b);
}

// ---------- prep: pack comparator-form coords ----------
__global__ __launch_bounds__(256) void prep_kernel(
        const float* __restrict__ pre, const float* __restrict__ cur,
        float4* __restrict__ pre4, float4* __restrict__ cur4) {
    int i = blockIdx.x * 256 + threadIdx.x;
    if (i < N_CUR) {
        float x = cur[i], y = cur[N_CUR + i], z = cur[2 * N_CUR + i];
        cur4[i] = make_float4(x, y, z, fmaf(x, x, fmaf(y, y, z * z)));
    }
    if (i < N_PRE) {
        float x = pre[i], y = pre[N_PRE + i], z = pre[2 * N_PRE + i];
        pre4[i] = make_float4(-2.f * x, -2.f * y, -2.f * z,
                              fmaf(x, x, fmaf(y, y, z * z)));
    }
}

// ---------- Kernel A: cur2pre argmin (R6 structure, ~10us measured) ----
// Wave owns 2 cur queries; lanes scan pre candidates from the LDS tile.
// Branchless running min; strict < + ascending per-lane idx stream ->
// lowest index on ties; cross-lane packed u64 butterfly min.
#define TILE_A 2048

__global__ __launch_bounds__(1024) void cur2pre_kernel(
        const float4* __restrict__ pre4, const float4* __restrict__ cur4,
        unsigned* __restrict__ c2p) {
    __shared__ float4 sp[TILE_A];
    const int tid  = threadIdx.x;
    const int lane = tid & 63;
    const int w    = tid >> 6;
    const int j0   = blockIdx.x * 32 + w * 2;   // this wave's 2 cur points

    const float4 c0 = cur4[j0 + 0];
    const float4 c1 = cur4[j0 + 1];

    const float INF = __int_as_float(0x7F800000);
    float b0 = INF, b1 = INF;
    int   i0 = 0,   i1 = 0;

    for (int tile = 0; tile < N_PRE; tile += TILE_A) {
        __syncthreads();
        for (int k = tid; k < TILE_A; k += 1024) sp[k] = pre4[tile + k];
        __syncthreads();

#pragma unroll 8
        for (int s = 0; s < TILE_A; s += 64) {
            float4 q = sp[s + lane];
            int idx = tile + s + lane;
            float d; bool c;
            d = fmaf(q.x, c0.x, fmaf(q.y, c0.y, fmaf(q.z, c0.z, q.w)));
            c = d < b0; b0 = c ? d : b0; i0 = c ? idx : i0;
            d = fmaf(q.x, c1.x, fmaf(q.y, c1.y, fmaf(q.z, c1.z, q.w)));
            c = d < b1; b1 = c ? d : b1; i1 = c ? idx : i1;
        }
    }

    unsigned long long v0 =
        (((unsigned long long)key_of_bits(__float_as_uint(b0))) << 32) | (unsigned)i0;
    unsigned long long v1 =
        (((unsigned long long)key_of_bits(__float_as_uint(b1))) << 32) | (unsigned)i1;
#pragma unroll
    for (int off = 32; off > 0; off >>= 1) {
        unsigned long long o;
        o = __shfl_xor(v0, off); v0 = (o < v0) ? o : v0;
        o = __shfl_xor(v1, off); v1 = (o < v1) ? o : v1;
    }
    unsigned r = (unsigned)v0;
    r = (lane == 1) ? (unsigned)v1 : r;
    if (lane < 2) c2p[j0 + lane] = r;
}

// ---------- Kernel B: per-pre top-8 + masked mean (P=4, prefetch) ------
// 512 blocks x 256 thr (4 waves); wave owns 4 pres; unsplit candidate
// stream. Pop event path proven R4 (DPP row_shr:1 + readlane). Lists
// are replicated per 16-lane DPP row -> finalize row r = list r.
#define TILE_B 2048

__device__ __forceinline__ void pop_top8(float d, float& t8, unsigned& ld,
                                         unsigned& li, int jbase) {
    unsigned long long m = __ballot(d < t8);
    while (m) {
        int src = __ffsll(m) - 1;
        unsigned fdb = (unsigned)__builtin_amdgcn_readlane(__float_as_int(d), src);
        unsigned kd = key_of_bits(fdb);            // uniform (SALU)
        unsigned kj = (unsigned)(jbase + src);     // uniform (SALU)
        // shift-up within 16-lane row; row-lane 0 receives old=0 (kd<0u
        // never true -> slot 0 never takes the shifted value)
        unsigned ud = (unsigned)__builtin_amdgcn_update_dpp(
            0, (int)ld, 0x111, 0xF, 0xF, false);
        unsigned uj = (unsigned)__builtin_amdgcn_update_dpp(
            0, (int)li, 0x111, 0xF, 0xF, false);
        bool hi = kd < ud;   // belongs below slot-1 -> take shifted value
        bool lo = kd < ld;   // belongs here -> take new
        ld = hi ? ud : (lo ? kd : ld);
        li = hi ? uj : (lo ? kj : li);
        unsigned k7 = (unsigned)__builtin_amdgcn_readlane((int)ld, 7);
        t8 = float_of_key(k7);
        m = (m & (m - 1)) & __ballot(d < t8);
    }
}

__global__ __launch_bounds__(256) void knn_finalize_kernel(
        const float4* __restrict__ pre4, const float4* __restrict__ cur4,
        const float* __restrict__ ups,
        const unsigned* __restrict__ c2p,
        float* __restrict__ out) {
    __shared__ float4 sc[TILE_B];
    const int tid  = threadIdx.x;
    const int lane = tid & 63;
    const int w    = tid >> 6;                  // 0..3
    const int ia   = blockIdx.x * 16 + w * 4;   // this wave's 4 pres

    const float4 p0 = pre4[ia + 0];   // (-2p, |p|^2), wave-uniform
    const float4 p1 = pre4[ia + 1];
    const float4 p2 = pre4[ia + 2];
    const float4 p3 = pre4[ia + 3];

    const float INF = __int_as_float(0x7F800000);
    unsigned ld0 = MAPPED_INF, li0 = 0, ld1 = MAPPED_INF, li1 = 0;
    unsigned ld2 = MAPPED_INF, li2 = 0, ld3 = MAPPED_INF, li3 = 0;
    float t0 = INF, t1 = INF, t2 = INF, t3 = INF;

    for (int tile = 0; tile < N_CUR; tile += TILE_B) {
        __syncthreads();
        for (int k = tid; k < TILE_B; k += 256) sc[k] = cur4[tile + k];
        __syncthreads();

        float4 c = sc[lane];                    // preload chunk 0
#pragma unroll 4
        for (int s = 0; s < TILE_B; s += 64) {
            // prefetch NEXT chunk before the (serializing) pop calls;
            // wrap on the last chunk -> harmless dummy read
            float4 cn = sc[((s + 64) & (TILE_B - 1)) + lane];
            float d0 = fmaf(p0.x, c.x, fmaf(p0.y, c.y, fmaf(p0.z, c.z, c.w)));
            float d1 = fmaf(p1.x, c.x, fmaf(p1.y, c.y, fmaf(p1.z, c.z, c.w)));
            float d2 = fmaf(p2.x, c.x, fmaf(p2.y, c.y, fmaf(p2.z, c.z, c.w)));
            float d3 = fmaf(p3.x, c.x, fmaf(p3.y, c.y, fmaf(p3.z, c.z, c.w)));
            const int jbase = tile + s;
            pop_top8(d0, t0, ld0, li0, jbase);
            pop_top8(d1, t1, ld1, li1, jbase);
            pop_top8(d2, t2, ld2, li2, jbase);
            pop_top8(d3, t3, ld3, li3, jbase);
            c = cn;
        }
    }

    // finalize all 4 lists in parallel: DPP row-replication means each
    // 16-lane row holds an identical copy of every list. Row r (lanes
    // 16r..16r+7) finalizes list r; slot = lane&15. shfl_xor 1/2/4 stays
    // within the 8-lane group. True distance recomputed in direct form.
    {
        const int row  = lane >> 4;   // 0..3 -> list index
        const int slot = lane & 15;

        unsigned j = li0;
        j = (row == 1) ? li1 : j;
        j = (row == 2) ? li2 : j;
        j = (row == 3) ? li3 : j;

        float acc = 0.f;
        if (slot < 8) {
            float4 pp = p0;
            pp = (row == 1) ? p1 : pp;
            pp = (row == 2) ? p2 : pp;
            pp = (row == 3) ? p3 : pp;
            float4 cc = cur4[j];
            float px = -0.5f * pp.x, py = -0.5f * pp.y, pz = -0.5f * pp.z;
            float dx = cc.x - px, dy = cc.y - py, dz = cc.z - pz;
            float dsq = fmaf(dx, dx, fmaf(dy, dy, dz * dz));
            acc = (c2p[j] == (unsigned)(ia + row)) ? sqrtf(dsq) : 0.f;
        }
        acc += __shfl_xor(acc, 1);
        acc += __shfl_xor(acc, 2);
        acc += __shfl_xor(acc, 4);
        if (slot == 0) out[ia + row] = acc / ups[ia + row];
    }
}

// ---------- launch ----------
extern "C" void kernel_launch(void* const* d_in, const int* in_sizes, int n_in,
                              void* d_out, int out_size, void* d_ws, size_t ws_size,
                              hipStream_t stream) {
    const float* pre = (const float*)d_in[0];   // (1,3,8192)
    const float* cur = (const float*)d_in[1];   // (1,3,16384)
    const float* ups = (const float*)d_in[2];   // (1,8192)
    float* out = (float*)d_out;                 // (1,8192)

    char* ws = (char*)d_ws;
    unsigned* c2p = (unsigned*)ws;                    //  64 KB
    float4*   pre4 = (float4*)(ws + 65536);           // 128 KB
    float4*   cur4 = (float4*)(ws + 65536 + 131072);  // 256 KB

    prep_kernel<<<N_CUR / 256, 256, 0, stream>>>(pre, cur, pre4, cur4);

    // A: 512 blocks x 16 waves, 2 cur/wave (R1/R6 config, ~10us)
    cur2pre_kernel<<<N_CUR / 32, 1024, 0, stream>>>(pre4, cur4, c2p);

    // B: 512 blocks x 4 waves, 4 pres/wave -> 2 independent blocks/CU
    knn_finalize_kernel<<<N_PRE / 16, 256, 0, stream>>>(pre4, cur4, ups, c2p, out);
}

// Round 8
// 136.330 us; speedup vs baseline: 1.1419x; 1.1419x over previous
//
#include <hip/hip_runtime.h>

// Problem constants (fixed by reference setup_inputs)
#define N_PRE 8192
#define N_CUR 16384
#define KNN   8

// Workspace layout (bytes):
//   [0,    64K) : c2p  u32[N_CUR]     nearest-pre index per cur point
//   [64K, 192K) : pre4 float4[N_PRE]  (-2px, -2py, -2pz, |p|^2)
//   [192K,448K) : cur4 float4[N_CUR]  ( cx,   cy,   cz,  |c|^2)
//
// Comparator trick: for a fixed query q, ordering by true sqdist equals
// ordering by (|cand|^2 - 2 cand.q)  -> 3 FMA per candidate.
// d can be NEGATIVE -> monotone float->u32 key map for all key compares.
//
// R8 ledger (re-audited with R6/R7 data): OH~31us, prep~2us,
// A(branchless LDS)~41us = VALU floor at 6 instr/pair, B best = 57.3 (R4).
//  A: cut to 4 instr/pair (3 FMA + 1 v_cmp) by moving (best,idx) tracking
//     to the SALU via ballot-pop — R3's failure mode (cold-start ballot
//     storm: bf=INF -> 64 serial pops on chunk 0) fixed by WARM START:
//     shfl-min chunk 0, locate first-idx via ballot(d==t), seed (bk,bi,bf).
//     Expected pops/query ~ ln(8192/64) ~ 5. Q=4, 16 waves/CU.
//  B: R4 verbatim (57.3us measured; R6 split +events and R7 P=4 both lost).

#define MAPPED_INF 0xFF800000u  // monotone key of +inf (empty-slot sentinel)

__device__ __forceinline__ unsigned key_of_bits(unsigned b) {
    return b ^ (0x80000000u | (unsigned)((int)b >> 31));
}
__device__ __forceinline__ float float_of_key(unsigned k) {
    unsigned b = k ^ (0x80000000u | ~(unsigned)((int)k >> 31));
    return __uint_as_float(b);
}

// ---------- prep: pack comparator-form coords ----------
__global__ __launch_bounds__(256) void prep_kernel(
        const float* __restrict__ pre, const float* __restrict__ cur,
        float4* __restrict__ pre4, float4* __restrict__ cur4) {
    int i = blockIdx.x * 256 + threadIdx.x;
    if (i < N_CUR) {
        float x = cur[i], y = cur[N_CUR + i], z = cur[2 * N_CUR + i];
        cur4[i] = make_float4(x, y, z, fmaf(x, x, fmaf(y, y, z * z)));
    }
    if (i < N_PRE) {
        float x = pre[i], y = pre[N_PRE + i], z = pre[2 * N_PRE + i];
        pre4[i] = make_float4(-2.f * x, -2.f * y, -2.f * z,
                              fmaf(x, x, fmaf(y, y, z * z)));
    }
}

// ---------- Kernel A: cur2pre argmin (ballot-pop + warm start) ----------
// Wave owns Q=4 cur queries; best state (bk=key, bi=idx, bf=float) is
// wave-uniform (SGPRs). Fast path per pair: 3 FMA + 1 v_cmp; pops go
// ballot -> s_ff1 -> readlane -> SALU compare. Ascending scan + strict <
// on keys -> lowest index on ties (same as all prior rounds).
#define TILE_A 2048
#define Q_A 4

__device__ __forceinline__ void warmA(float d, unsigned& bk, unsigned& bi,
                                      float& bf) {
    float t = d;
    t = fminf(t, __shfl_xor(t, 32));
    t = fminf(t, __shfl_xor(t, 16));
    t = fminf(t, __shfl_xor(t, 8));
    t = fminf(t, __shfl_xor(t, 4));
    t = fminf(t, __shfl_xor(t, 2));
    t = fminf(t, __shfl_xor(t, 1));
    unsigned long long e = __ballot(d == t);     // non-empty: t came from a lane
    int src = __ffsll(e) - 1;                    // first index achieving min
    unsigned fdb = (unsigned)__builtin_amdgcn_readlane(__float_as_int(d), src);
    bk = key_of_bits(fdb);
    bi = (unsigned)src;                          // chunk 0 -> global idx = src
    bf = __uint_as_float(fdb);
}

__device__ __forceinline__ void popA(float d, float& bf, unsigned& bk,
                                     unsigned& bi, int sbase) {
    unsigned long long m = __ballot(d < bf);
    while (m) {
        int src = __ffsll(m) - 1;
        unsigned fdb = (unsigned)__builtin_amdgcn_readlane(__float_as_int(d), src);
        unsigned kd = key_of_bits(fdb);
        if (kd < bk) {                 // uniform: SALU
            bk = kd;
            bi = (unsigned)(sbase + src);
            bf = __uint_as_float(fdb);
        }
        m &= m - 1;
    }
}

__global__ __launch_bounds__(512) void cur2pre_kernel(
        const float4* __restrict__ pre4, const float4* __restrict__ cur4,
        unsigned* __restrict__ c2p) {
    __shared__ float4 sp[TILE_A];
    const int tid  = threadIdx.x;
    const int lane = tid & 63;
    const int w    = tid >> 6;                  // 0..7
    const int j0   = (blockIdx.x * 8 + w) * Q_A;

    const float4 c0 = cur4[j0 + 0];
    const float4 c1 = cur4[j0 + 1];
    const float4 c2 = cur4[j0 + 2];
    const float4 c3 = cur4[j0 + 3];

    // stage tile 0, then warm-start from chunk 0 (candidates 0..63)
    for (int k = tid; k < TILE_A; k += 512) sp[k] = pre4[k];
    __syncthreads();

    unsigned bk0, bk1, bk2, bk3, bi0, bi1, bi2, bi3;
    float bf0, bf1, bf2, bf3;
    {
        float4 q = sp[lane];
        float d0 = fmaf(q.x, c0.x, fmaf(q.y, c0.y, fmaf(q.z, c0.z, q.w)));
        float d1 = fmaf(q.x, c1.x, fmaf(q.y, c1.y, fmaf(q.z, c1.z, q.w)));
        float d2 = fmaf(q.x, c2.x, fmaf(q.y, c2.y, fmaf(q.z, c2.z, q.w)));
        float d3 = fmaf(q.x, c3.x, fmaf(q.y, c3.y, fmaf(q.z, c3.z, q.w)));
        warmA(d0, bk0, bi0, bf0);
        warmA(d1, bk1, bi1, bf1);
        warmA(d2, bk2, bi2, bf2);
        warmA(d3, bk3, bi3, bf3);
    }

    for (int tile = 0; tile < N_PRE; tile += TILE_A) {
        if (tile > 0) {
            __syncthreads();
            for (int k = tid; k < TILE_A; k += 512) sp[k] = pre4[tile + k];
            __syncthreads();
        }
#pragma unroll 4
        for (int s = 0; s < TILE_A; s += 64) {
            float4 q = sp[s + lane];
            const int sb = tile + s;
            float d0 = fmaf(q.x, c0.x, fmaf(q.y, c0.y, fmaf(q.z, c0.z, q.w)));
            float d1 = fmaf(q.x, c1.x, fmaf(q.y, c1.y, fmaf(q.z, c1.z, q.w)));
            float d2 = fmaf(q.x, c2.x, fmaf(q.y, c2.y, fmaf(q.z, c2.z, q.w)));
            float d3 = fmaf(q.x, c3.x, fmaf(q.y, c3.y, fmaf(q.z, c3.z, q.w)));
            popA(d0, bf0, bk0, bi0, sb);
            popA(d1, bf1, bk1, bi1, sb);
            popA(d2, bf2, bk2, bi2, sb);
            popA(d3, bf3, bk3, bi3, sb);
        }
    }

    // results are wave-uniform; lane q writes query q's best index
    unsigned r = bi0;
    r = (lane == 1) ? bi1 : r;
    r = (lane == 2) ? bi2 : r;
    r = (lane == 3) ? bi3 : r;
    if (lane < 4) c2p[j0 + lane] = r;
}

// ---------- Kernel B: per-pre top-8 + masked mean (R4 verbatim, 57.3us) --
// 512 blocks x 512 thr; wave owns P=2 pres; LDS cur tile; ballot-gated
// pop events with DPP row_shr:1 + readlane insert (no LDS-pipe ops).
#define TILE_B 2048

__device__ __forceinline__ void pop_top8(float d, float& t8, unsigned& ld,
                                         unsigned& li, int jbase) {
    unsigned long long m = __ballot(d < t8);
    while (m) {
        int src = __ffsll(m) - 1;
        unsigned fdb = (unsigned)__builtin_amdgcn_readlane(__float_as_int(d), src);
        unsigned kd = key_of_bits(fdb);            // uniform (SALU)
        unsigned kj = (unsigned)(jbase + src);     // uniform (SALU)
        // shift-up within 16-lane row; lane 0 receives old=0 (kd<0u never
        // true -> slot 0 never takes the shifted value)
        unsigned ud = (unsigned)__builtin_amdgcn_update_dpp(
            0, (int)ld, 0x111, 0xF, 0xF, false);
        unsigned uj = (unsigned)__builtin_amdgcn_update_dpp(
            0, (int)li, 0x111, 0xF, 0xF, false);
        bool hi = kd < ud;   // belongs below slot-1 -> take shifted value
        bool lo = kd < ld;   // belongs here -> take new
        ld = hi ? ud : (lo ? kd : ld);
        li = hi ? uj : (lo ? kj : li);
        unsigned k7 = (unsigned)__builtin_amdgcn_readlane((int)ld, 7);
        t8 = float_of_key(k7);
        m = (m & (m - 1)) & __ballot(d < t8);
    }
}

__global__ __launch_bounds__(512) void knn_finalize_kernel(
        const float4* __restrict__ pre4, const float4* __restrict__ cur4,
        const float* __restrict__ ups,
        const unsigned* __restrict__ c2p,
        float* __restrict__ out) {
    __shared__ float4 sc[TILE_B];
    const int tid  = threadIdx.x;
    const int lane = tid & 63;
    const int w    = tid >> 6;
    const int ia   = blockIdx.x * 16 + w * 2;   // 8 waves x 2 pres each
    const int ib   = ia + 1;

    const float4 p0 = pre4[ia];   // (-2p, |p|^2), wave-uniform
    const float4 p1 = pre4[ib];

    const float INF = __int_as_float(0x7F800000);
    unsigned ld0 = MAPPED_INF, li0 = 0, ld1 = MAPPED_INF, li1 = 0;
    float t80 = INF, t81 = INF;

    for (int tile = 0; tile < N_CUR; tile += TILE_B) {
        __syncthreads();
        for (int k = tid; k < TILE_B; k += 512) sc[k] = cur4[tile + k];
        __syncthreads();

#pragma unroll 4
        for (int s = 0; s < TILE_B; s += 64) {
            float4 c = sc[s + lane];
            float d0 = fmaf(p0.x, c.x, fmaf(p0.y, c.y, fmaf(p0.z, c.z, c.w)));
            float d1 = fmaf(p1.x, c.x, fmaf(p1.y, c.y, fmaf(p1.z, c.z, c.w)));
            const int jbase = tile + s;
            pop_top8(d0, t80, ld0, li0, jbase);
            pop_top8(d1, t81, ld1, li1, jbase);
        }
    }

    // finalize: lanes 0..7 hold slots 0..7 (ascending) of each list.
    // True distance recomputed in direct form; p recovered exactly (*-0.5).
    {
        float acc = 0.f;
        if (lane < 8) {
            unsigned j = li0;
            float4 cc = cur4[j];
            float px = -0.5f * p0.x, py = -0.5f * p0.y, pz = -0.5f * p0.z;
            float dx = cc.x - px, dy = cc.y - py, dz = cc.z - pz;
            float dsq = fmaf(dx, dx, fmaf(dy, dy, dz * dz));
            acc = (c2p[j] == (unsigned)ia) ? sqrtf(dsq) : 0.f;
        }
        acc += __shfl_xor(acc, 1);
        acc += __shfl_xor(acc, 2);
        acc += __shfl_xor(acc, 4);
        if (lane == 0) out[ia] = acc / ups[ia];
    }
    {
        float acc = 0.f;
        if (lane < 8) {
            unsigned j = li1;
            float4 cc = cur4[j];
            float px = -0.5f * p1.x, py = -0.5f * p1.y, pz = -0.5f * p1.z;
            float dx = cc.x - px, dy = cc.y - py, dz = cc.z - pz;
            float dsq = fmaf(dx, dx, fmaf(dy, dy, dz * dz));
            acc = (c2p[j] == (unsigned)ib) ? sqrtf(dsq) : 0.f;
        }
        acc += __shfl_xor(acc, 1);
        acc += __shfl_xor(acc, 2);
        acc += __shfl_xor(acc, 4);
        if (lane == 0) out[ib] = acc / ups[ib];
    }
}

// ---------- launch ----------
extern "C" void kernel_launch(void* const* d_in, const int* in_sizes, int n_in,
                              void* d_out, int out_size, void* d_ws, size_t ws_size,
                              hipStream_t stream) {
    const float* pre = (const float*)d_in[0];   // (1,3,8192)
    const float* cur = (const float*)d_in[1];   // (1,3,16384)
    const float* ups = (const float*)d_in[2];   // (1,8192)
    float* out = (float*)d_out;                 // (1,8192)

    char* ws = (char*)d_ws;
    unsigned* c2p = (unsigned*)ws;                    //  64 KB
    float4*   pre4 = (float4*)(ws + 65536);           // 128 KB
    float4*   cur4 = (float4*)(ws + 65536 + 131072);  // 256 KB

    prep_kernel<<<N_CUR / 256, 256, 0, stream>>>(pre, cur, pre4, cur4);

    // A: 512 blocks x 8 waves, Q=4 queries/wave -> 16 waves/CU
    cur2pre_kernel<<<N_CUR / (Q_A * 8), 512, 0, stream>>>(pre4, cur4, c2p);

    // B: 512 blocks x 8 waves, P=2 pres/wave (R4 config)
    knn_finalize_kernel<<<N_PRE / 16, 512, 0, stream>>>(pre4, cur4, ups, c2p, out);
}

// Round 10
// 119.380 us; speedup vs baseline: 1.3040x; 1.1420x over previous
//
#include <hip/hip_runtime.h>

// Problem constants (fixed by reference setup_inputs)
#define N_PRE 8192
#define N_CUR 16384
#define KNN   8

// Workspace layout (bytes):
//   [0,    64K) : c2p   u32[N_CUR]        nearest-pre index per cur point
//   [64K, 192K) : pre4  float4[N_PRE]     (-2px, -2py, -2pz, |p|^2)
//   [192K,448K) : cur4  float4[N_CUR]     ( cx,   cy,   cz,  |c|^2)
//   [448K,704K) : lists u32[N_PRE*8]      per-pre top-8 cur indices
//
// Comparator trick: for a fixed query q, ordering by true sqdist equals
// ordering by (|cand|^2 - 2 cand.q)  -> 3 FMA per candidate.
// d can be NEGATIVE -> monotone float->u32 key map for all key compares.
//
// R10 (R9 post-mortem: the spin-wait gated forward progress on all-block
// co-residency -> deadlock -> container timeout. Fix: DELETE the
// dependency, not synchronize it):
//  * fused_ab = A-waves (8/block, Q=4 branchless min, R6-proven) +
//    B-MAIN waves (8/block, P=2 ballot-pop, R4-proven). B-main needs
//    nothing from A: no atomics, no spin, no cross-block communication.
//    One barrier-matched staging loop (16 KB pre tile + 32 KB cur tile
//    per iter; barriers outside the wave-uniform A/B branch).
//    A writes c2p; B writes its top-8 index lists to workspace.
//  * finalize (3rd tiny launch, ~2-3us): 8-lane group per pre recomputes
//    true distances, masks by c2p ownership, reduces, divides by ups.
//  Rationale: serial A+B = 98us with VALU idle ~half of B's run (B: 48%
//  VALUBusy); co-resident A-waves fill B's stall slots. A-waves idling
//  at the barrier don't block B's issue.

#define MAPPED_INF 0xFF800000u  // monotone key of +inf (empty-slot sentinel)

#define NITER  8
#define ATILE  1024   // pre4 staged per iteration (16 KB)
#define BTILE  2048   // cur4 staged per iteration (32 KB)

__device__ __forceinline__ unsigned key_of_bits(unsigned b) {
    return b ^ (0x80000000u | (unsigned)((int)b >> 31));
}
__device__ __forceinline__ float float_of_key(unsigned k) {
    unsigned b = k ^ (0x80000000u | ~(unsigned)((int)k >> 31));
    return __uint_as_float(b);
}

// ---------- prep: pack comparator-form coords ----------
__global__ __launch_bounds__(256) void prep_kernel(
        const float* __restrict__ pre, const float* __restrict__ cur,
        float4* __restrict__ pre4, float4* __restrict__ cur4) {
    int i = blockIdx.x * 256 + threadIdx.x;
    if (i < N_CUR) {
        float x = cur[i], y = cur[N_CUR + i], z = cur[2 * N_CUR + i];
        cur4[i] = make_float4(x, y, z, fmaf(x, x, fmaf(y, y, z * z)));
    }
    if (i < N_PRE) {
        float x = pre[i], y = pre[N_PRE + i], z = pre[2 * N_PRE + i];
        pre4[i] = make_float4(-2.f * x, -2.f * y, -2.f * z,
                              fmaf(x, x, fmaf(y, y, z * z)));
    }
}

// ---------- B-side pop: top-8 on lanes 0..7, DPP shift-up insert -------
__device__ __forceinline__ void pop_top8(float d, float& t8, unsigned& ld,
                                         unsigned& li, int jbase) {
    unsigned long long m = __ballot(d < t8);
    while (m) {
        int src = __ffsll(m) - 1;
        unsigned fdb = (unsigned)__builtin_amdgcn_readlane(__float_as_int(d), src);
        unsigned kd = key_of_bits(fdb);            // uniform (SALU)
        unsigned kj = (unsigned)(jbase + src);     // uniform (SALU)
        // shift-up within 16-lane row; lane 0 receives old=0 (kd<0u never
        // true -> slot 0 never takes the shifted value)
        unsigned ud = (unsigned)__builtin_amdgcn_update_dpp(
            0, (int)ld, 0x111, 0xF, 0xF, false);
        unsigned uj = (unsigned)__builtin_amdgcn_update_dpp(
            0, (int)li, 0x111, 0xF, 0xF, false);
        bool hi = kd < ud;   // belongs below slot-1 -> take shifted value
        bool lo = kd < ld;   // belongs here -> take new
        ld = hi ? ud : (lo ? kd : ld);
        li = hi ? uj : (lo ? kj : li);
        unsigned k7 = (unsigned)__builtin_amdgcn_readlane((int)ld, 7);
        t8 = float_of_key(k7);
        m = (m & (m - 1)) & __ballot(d < t8);
    }
}

// ---------- fused kernel: A-waves + B-main waves, no cross-block deps --
__global__ __launch_bounds__(1024, 8) void fused_ab(
        const float4* __restrict__ pre4, const float4* __restrict__ cur4,
        unsigned* __restrict__ c2p, unsigned* __restrict__ lists) {
    __shared__ float4 sA[ATILE];   // pre tile (A-waves consume)
    __shared__ float4 sB[BTILE];   // cur tile (B-waves consume)

    const int tid  = threadIdx.x;
    const int lane = tid & 63;
    const int w    = tid >> 6;          // 0..15
    const bool isB = (w < 8);

    // B-waves: 2 pres each.  A-waves: 4 curs each.
    const int ia = blockIdx.x * 16 + w * 2;          // B: pres [ia, ia+1]
    const int wa = w - 8;                            // A wave index 0..7
    const int j0 = blockIdx.x * 32 + wa * 4;         // A: curs [j0, j0+4)

    float4 p0, p1, c0, c1, c2, c3;
    if (isB) {
        p0 = pre4[ia];
        p1 = pre4[ia + 1];
    } else {
        c0 = cur4[j0 + 0];
        c1 = cur4[j0 + 1];
        c2 = cur4[j0 + 2];
        c3 = cur4[j0 + 3];
    }

    const float INF = __int_as_float(0x7F800000);
    // B state: top-8 lists (lanes 0..7 ascending) for 2 pres
    unsigned ld0 = MAPPED_INF, li0 = 0, ld1 = MAPPED_INF, li1 = 0;
    float t80 = INF, t81 = INF;
    // A state: branchless running min for 4 curs
    float b0 = INF, b1 = INF, b2 = INF, b3 = INF;
    int   i0 = 0,  i1 = 0,  i2 = 0,  i3 = 0;

    for (int it = 0; it < NITER; ++it) {
        __syncthreads();
        // cooperative staging by all 1024 threads: 2x cur4 + 1x pre4 each
        sB[tid]        = cur4[it * BTILE + tid];
        sB[tid + 1024] = cur4[it * BTILE + 1024 + tid];
        sA[tid]        = pre4[it * ATILE + tid];
        __syncthreads();

        if (isB) {
#pragma unroll 4
            for (int s = 0; s < BTILE; s += 64) {
                float4 c = sB[s + lane];
                float d0 = fmaf(p0.x, c.x, fmaf(p0.y, c.y, fmaf(p0.z, c.z, c.w)));
                float d1 = fmaf(p1.x, c.x, fmaf(p1.y, c.y, fmaf(p1.z, c.z, c.w)));
                const int jbase = it * BTILE + s;
                pop_top8(d0, t80, ld0, li0, jbase);
                pop_top8(d1, t81, ld1, li1, jbase);
            }
        } else {
#pragma unroll 4
            for (int s = 0; s < ATILE; s += 64) {
                float4 q = sA[s + lane];
                int idx = it * ATILE + s + lane;
                float d; bool c;
                d = fmaf(q.x, c0.x, fmaf(q.y, c0.y, fmaf(q.z, c0.z, q.w)));
                c = d < b0; b0 = c ? d : b0; i0 = c ? idx : i0;
                d = fmaf(q.x, c1.x, fmaf(q.y, c1.y, fmaf(q.z, c1.z, q.w)));
                c = d < b1; b1 = c ? d : b1; i1 = c ? idx : i1;
                d = fmaf(q.x, c2.x, fmaf(q.y, c2.y, fmaf(q.z, c2.z, q.w)));
                c = d < b2; b2 = c ? d : b2; i2 = c ? idx : i2;
                d = fmaf(q.x, c3.x, fmaf(q.y, c3.y, fmaf(q.z, c3.z, q.w)));
                c = d < b3; b3 = c ? d : b3; i3 = c ? idx : i3;
            }
        }
    }
    // no barriers below this point

    if (!isB) {
        // ---- A epilogue: packed (key,idx) butterfly min, write c2p ----
        unsigned long long v0 =
            (((unsigned long long)key_of_bits(__float_as_uint(b0))) << 32) | (unsigned)i0;
        unsigned long long v1 =
            (((unsigned long long)key_of_bits(__float_as_uint(b1))) << 32) | (unsigned)i1;
        unsigned long long v2 =
            (((unsigned long long)key_of_bits(__float_as_uint(b2))) << 32) | (unsigned)i2;
        unsigned long long v3 =
            (((unsigned long long)key_of_bits(__float_as_uint(b3))) << 32) | (unsigned)i3;
#pragma unroll
        for (int off = 32; off > 0; off >>= 1) {
            unsigned long long o;
            o = __shfl_xor(v0, off); v0 = (o < v0) ? o : v0;
            o = __shfl_xor(v1, off); v1 = (o < v1) ? o : v1;
            o = __shfl_xor(v2, off); v2 = (o < v2) ? o : v2;
            o = __shfl_xor(v3, off); v3 = (o < v3) ? o : v3;
        }
        unsigned r = (unsigned)v0;
        r = (lane == 1) ? (unsigned)v1 : r;
        r = (lane == 2) ? (unsigned)v2 : r;
        r = (lane == 3) ? (unsigned)v3 : r;
        if (lane < 4) c2p[j0 + lane] = r;
    } else {
        // ---- B epilogue: dump top-8 index lists (lanes 0..7, ascending)
        if (lane < 8) {
            lists[ia * 8 + lane] = li0;
            lists[(ia + 1) * 8 + lane] = li1;
        }
    }
}

// ---------- finalize: masked mean from lists + c2p (tiny, ~2-3us) ------
__global__ __launch_bounds__(256) void finalize_kernel(
        const float4* __restrict__ pre4, const float4* __restrict__ cur4,
        const float* __restrict__ ups,
        const unsigned* __restrict__ c2p, const unsigned* __restrict__ lists,
        float* __restrict__ out) {
    const int t    = blockIdx.x * 256 + threadIdx.x;  // 0 .. 65535
    const int pg   = t >> 3;
    const int slot = t & 7;

    unsigned j = lists[t];
    float4 cc = cur4[j];
    float4 pp = pre4[pg];
    // True distance recomputed in direct form; p recovered exactly (*-0.5).
    float px = -0.5f * pp.x, py = -0.5f * pp.y, pz = -0.5f * pp.z;
    float dx = cc.x - px, dy = cc.y - py, dz = cc.z - pz;
    float dsq = fmaf(dx, dx, fmaf(dy, dy, dz * dz));
    float acc = (c2p[j] == (unsigned)pg) ? sqrtf(dsq) : 0.f;

    // 8-lane group reduce (groups are 8-aligned within the wave)
    acc += __shfl_xor(acc, 1);
    acc += __shfl_xor(acc, 2);
    acc += __shfl_xor(acc, 4);
    if (slot == 0) out[pg] = acc / ups[pg];
}

// ---------- launch ----------
extern "C" void kernel_launch(void* const* d_in, const int* in_sizes, int n_in,
                              void* d_out, int out_size, void* d_ws, size_t ws_size,
                              hipStream_t stream) {
    const float* pre = (const float*)d_in[0];   // (1,3,8192)
    const float* cur = (const float*)d_in[1];   // (1,3,16384)
    const float* ups = (const float*)d_in[2];   // (1,8192)
    float* out = (float*)d_out;                 // (1,8192)

    char* ws = (char*)d_ws;
    unsigned* c2p   = (unsigned*)ws;                          //  64 KB
    float4*   pre4  = (float4*)(ws + 65536);                  // 128 KB
    float4*   cur4  = (float4*)(ws + 65536 + 131072);         // 256 KB
    unsigned* lists = (unsigned*)(ws + 65536 + 131072 + 262144); // 256 KB

    prep_kernel<<<N_CUR / 256, 256, 0, stream>>>(pre, cur, pre4, cur4);

    // 512 blocks x 16 waves (8 B-main + 8 A); no cross-block dependencies.
    fused_ab<<<512, 1024, 0, stream>>>(pre4, cur4, c2p, lists);

    // 8192 pres x 8 slots = 65536 threads
    finalize_kernel<<<N_PRE * 8 / 256, 256, 0, stream>>>(
        pre4, cur4, ups, c2p, lists, out);
}